// Round 2
// baseline (335.240 us; speedup 1.0000x reference)
//
#include <hip/hip_runtime.h>

// CollisionLoss: B x (7 left) x (7 right) segment-segment squared distances,
// masked exp(-d2) sum / B.
// R2: branchless Ericson closest-point (algebraically identical to the
// reference's jnp.where region cascade), v_rcp_f32 instead of precise
// division, all 48 node floats in registers, 49 pairs fully unrolled.
// The reference cascade == Ericson: s0=clamp((be-cd)/det) [det>0 else 0],
// tn=b*s0+e, t=clamp(tn/c); if tn<0: s=clamp(-d/a); if tn>c: s=clamp((b-d)/a);
// else s=s0.  Verified region-by-region; ties are measure-zero and perturb
// the loss by <= exp(0)/B ~ 4e-6 << 2.8e-2 threshold.

__device__ __forceinline__ float rcpf(float x) { return __builtin_amdgcn_rcpf(x); }
__device__ __forceinline__ float clamp01(float x) {
    return __builtin_amdgcn_fmed3f(x, 0.0f, 1.0f);
}

__device__ __forceinline__ float cap_dist2(
    float px0, float py0, float pz0, float px1, float py1, float pz1,
    float qx0, float qy0, float qz0, float qx1, float qy1, float qz1)
{
    const float dpx = px1 - px0, dpy = py1 - py0, dpz = pz1 - pz0;
    const float dqx = qx1 - qx0, dqy = qy1 - qy0, dqz = qz1 - qz0;
    const float rx  = px0 - qx0, ry  = py0 - qy0, rz  = pz0 - qz0;

    const float a = dpx*dpx + dpy*dpy + dpz*dpz;   // >0 w.p. 1 (gaussian)
    const float c = dqx*dqx + dqy*dqy + dqz*dqz;   // >0 w.p. 1
    const float b = dpx*dqx + dpy*dqy + dpz*dqz;
    const float d = dpx*rx + dpy*ry + dpz*rz;
    const float e = dqx*rx + dqy*ry + dqz*rz;
    const float det = a*c - b*b;

    const float rcp_a = rcpf(a);
    const float rcp_c = rcpf(c);

    // s0 = det>0 ? clamp((be-cd)/det) : 0   (cndmask kills the inf/NaN path)
    const float f  = b*e - c*d;
    const float s0 = (det > 0.0f) ? clamp01(f * rcpf(det)) : 0.0f;

    const float tn = b*s0 + e;                 // t numerator (denominator c)
    const float t  = clamp01(tn * rcp_c);

    // recompute s only where t was clamped (two cndmasks)
    const float sA = clamp01(-d * rcp_a);          // t clamped to 0
    const float sB = clamp01((b - d) * rcp_a);     // t clamped to 1
    const float s  = (tn < 0.0f) ? sA : ((tn > c) ? sB : s0);

    const float wx = rx + s*dpx - t*dqx;
    const float wy = ry + s*dpy - t*dqy;
    const float wz = rz + s*dpz - t*dqz;
    return wx*wx + wy*wy + wz*wz;
}

// grid = B/256 = 1024 blocks = 4 blocks/CU = 4 waves/EU -> cap VGPR at 128
__global__ __launch_bounds__(256, 4) void collision_loss_kernel(
    const float* __restrict__ pos,
    const float* __restrict__ rot,
    float* __restrict__ out,
    int B)
{
    __shared__ float wsum[4];

    const int tid = threadIdx.x;
    const int b   = blockIdx.x * 256 + tid;

    float sum = 0.0f;

    if (b < B) {
        // ---- pos: 42 floats as 21 float2 (8B-aligned base), all -> registers
        const float2* p2 = reinterpret_cast<const float2*>(pos + (size_t)b * 42);
        float P[48];   // floats 0..20: left nodes 0..6; 21..41: right nodes 7..13
                       // 42..44: handL; 45..47: handR
        #pragma unroll
        for (int k = 0; k < 21; ++k) {
            float2 u = p2[k];
            P[2*k]     = u.x;
            P[2*k + 1] = u.y;
        }

        // ---- rot third column for EE nodes 6 and 13 ----
        const float* rb = rot + (size_t)b * 126;
        const float r6x = rb[ 56], r6y = rb[ 59], r6z = rb[ 62];  // node 6 col2
        const float rdx = rb[119], rdy = rb[122], rdz = rb[125];  // node13 col2

        P[42] = P[18] + 0.2f * r6x;   // handL = node6  + 0.2*col2
        P[43] = P[19] + 0.2f * r6y;
        P[44] = P[20] + 0.2f * r6z;
        P[45] = P[39] + 0.2f * rdx;   // handR = node13 + 0.2*col2
        P[46] = P[40] + 0.2f * rdy;
        P[47] = P[41] + 0.2f * rdz;

        // ---- 7x7 pairs, fully unrolled, all static register indexing ----
        // left segment j: p0 = node j (P[3j]),  p1 = (j<6 ? node j+1 : handL)
        // right segment i: q0 = node 7+i (P[21+3i]), q1 = (i<6 ? node 8+i : handR)
        #pragma unroll
        for (int i = 0; i < 7; ++i) {
            const int q0o = 21 + 3*i;
            const int q1o = (i < 6) ? (24 + 3*i) : 45;
            const float q0x = P[q0o], q0y = P[q0o+1], q0z = P[q0o+2];
            const float q1x = P[q1o], q1y = P[q1o+1], q1z = P[q1o+2];
            #pragma unroll
            for (int j = 0; j < 7; ++j) {
                const int p0o = 3*j;
                const int p1o = (j < 6) ? (3*j + 3) : 42;
                const float d2 = cap_dist2(
                    P[p0o], P[p0o+1], P[p0o+2],
                    P[p1o], P[p1o+1], P[p1o+2],
                    q0x, q0y, q0z, q1x, q1y, q1z);
                bool m;
                if (i == 6 && j == 6) {
                    m = (d2 > 0.09f);                 // special [6,6]: far mask
                } else {
                    m = (d2 < 0.01f) && (d2 > 0.0f);  // collision mask
                }
                // branchless accumulate: exp always computed, cndmask'd add
                sum += m ? __expf(-d2) : 0.0f;
            }
        }
    }

    // ---- reduction: wave shuffle -> LDS -> one atomic per block ----
    #pragma unroll
    for (int off = 32; off > 0; off >>= 1)
        sum += __shfl_down(sum, off, 64);
    const int wave = tid >> 6;
    if ((tid & 63) == 0) wsum[wave] = sum;
    __syncthreads();
    if (tid == 0) {
        float s = (wsum[0] + wsum[1]) + (wsum[2] + wsum[3]);
        atomicAdd(out, s * (1.0f / 262144.0f));  // exact pow2 scale = /B
    }
}

extern "C" void kernel_launch(void* const* d_in, const int* in_sizes, int n_in,
                              void* d_out, int out_size, void* d_ws, size_t ws_size,
                              hipStream_t stream) {
    const float* pos = (const float*)d_in[0];   // (B,14,3) f32
    const float* rot = (const float*)d_in[1];   // (B,14,9) f32
    float* out = (float*)d_out;

    const int B = in_sizes[0] / 42;             // 262144
    hipMemsetAsync(out, 0, sizeof(float), stream);

    const int grid = (B + 255) / 256;
    collision_loss_kernel<<<grid, 256, 0, stream>>>(pos, rot, out, B);
}

// Round 3
// 220.287 us; speedup vs baseline: 1.5218x; 1.5218x over previous
//
#include <hip/hip_runtime.h>

// CollisionLoss: B x (7 left) x (7 right) segment-segment squared distances,
// masked exp(-d2) sum / B.
// R3: branchless Ericson cascade (validated exact vs np ref in R2), and ALL
// per-thread state in named scalars -- R2's float P[48] array was demoted to
// scratch (WRITE_SIZE 289 MB = ~1.1 KB spilled/thread, dur 183us). No arrays
// anywhere => register residency is deterministic. No occupancy clamp (R2's
// __launch_bounds__(256,4) contributed to the demotion; R1 at VGPR=68 got
// 26% occupancy which was plenty -- we are not BW-bound).

__device__ __forceinline__ float rcpf(float x) { return __builtin_amdgcn_rcpf(x); }
__device__ __forceinline__ float clamp01(float x) {
    return __builtin_amdgcn_fmed3f(x, 0.0f, 1.0f);
}

__device__ __forceinline__ float cap_dist2(
    float px0, float py0, float pz0, float px1, float py1, float pz1,
    float qx0, float qy0, float qz0, float qx1, float qy1, float qz1)
{
    const float dpx = px1 - px0, dpy = py1 - py0, dpz = pz1 - pz0;
    const float dqx = qx1 - qx0, dqy = qy1 - qy0, dqz = qz1 - qz0;
    const float rx  = px0 - qx0, ry  = py0 - qy0, rz  = pz0 - qz0;

    const float a = dpx*dpx + dpy*dpy + dpz*dpz;   // >0 w.p. 1 (gaussian)
    const float c = dqx*dqx + dqy*dqy + dqz*dqz;   // >0 w.p. 1
    const float b = dpx*dqx + dpy*dqy + dpz*dqz;
    const float d = dpx*rx + dpy*ry + dpz*rz;
    const float e = dqx*rx + dqy*ry + dqz*rz;
    const float det = a*c - b*b;

    const float rcp_a = rcpf(a);
    const float rcp_c = rcpf(c);

    // s0 = det>0 ? clamp01((be-cd)/det) : 0  (cndmask kills the inf/NaN path)
    const float f  = b*e - c*d;
    const float s0 = (det > 0.0f) ? clamp01(f * rcpf(det)) : 0.0f;

    const float tn = b*s0 + e;                 // t numerator (denominator c)
    const float t  = clamp01(tn * rcp_c);

    // recompute s only where t was clamped (two cndmasks); ties measure-zero
    const float sA = clamp01(-d * rcp_a);          // t clamped to 0
    const float sB = clamp01((b - d) * rcp_a);     // t clamped to 1
    const float s  = (tn < 0.0f) ? sA : ((tn > c) ? sB : s0);

    const float wx = rx + s*dpx - t*dqx;
    const float wy = ry + s*dpy - t*dqy;
    const float wz = rz + s*dpz - t*dqz;
    return wx*wx + wy*wy + wz*wz;
}

__global__ __launch_bounds__(256) void collision_loss_kernel(
    const float* __restrict__ pos,
    const float* __restrict__ rot,
    float* __restrict__ out,
    int B)
{
    __shared__ float wsum[4];

    const int tid = threadIdx.x;
    const int b   = blockIdx.x * 256 + tid;

    float sum = 0.0f;

    if (b < B) {
        // ---- pos: 42 floats as 21 float2 (8B-aligned base) -> named scalars
        const float2* p2 = reinterpret_cast<const float2*>(pos + (size_t)b * 42);
        const float2 u0  = p2[0],  u1  = p2[1],  u2  = p2[2],  u3  = p2[3];
        const float2 u4  = p2[4],  u5  = p2[5],  u6  = p2[6],  u7  = p2[7];
        const float2 u8  = p2[8],  u9  = p2[9],  u10 = p2[10], u11 = p2[11];
        const float2 u12 = p2[12], u13 = p2[13], u14 = p2[14], u15 = p2[15];
        const float2 u16 = p2[16], u17 = p2[17], u18 = p2[18], u19 = p2[19];
        const float2 u20 = p2[20];

        // node n -> float indices 3n,3n+1,3n+2; float f lives in u(f/2).(x|y)
        const float n0x=u0.x,  n0y=u0.y,  n0z=u1.x;
        const float n1x=u1.y,  n1y=u2.x,  n1z=u2.y;
        const float n2x=u3.x,  n2y=u3.y,  n2z=u4.x;
        const float n3x=u4.y,  n3y=u5.x,  n3z=u5.y;
        const float n4x=u6.x,  n4y=u6.y,  n4z=u7.x;
        const float n5x=u7.y,  n5y=u8.x,  n5z=u8.y;
        const float n6x=u9.x,  n6y=u9.y,  n6z=u10.x;
        const float n7x=u10.y, n7y=u11.x, n7z=u11.y;
        const float n8x=u12.x, n8y=u12.y, n8z=u13.x;
        const float n9x=u13.y, n9y=u14.x, n9z=u14.y;
        const float n10x=u15.x, n10y=u15.y, n10z=u16.x;
        const float n11x=u16.y, n11y=u17.x, n11z=u17.y;
        const float n12x=u18.x, n12y=u18.y, n12z=u19.x;
        const float n13x=u19.y, n13y=u20.x, n13z=u20.y;

        // ---- rot third column for EE nodes 6 and 13 ----
        const float* rb = rot + (size_t)b * 126;
        const float hlx = n6x  + 0.2f * rb[ 56];   // handL = node6 + 0.2*col2
        const float hly = n6y  + 0.2f * rb[ 59];
        const float hlz = n6z  + 0.2f * rb[ 62];
        const float hrx = n13x + 0.2f * rb[119];   // handR = node13 + 0.2*col2
        const float hry = n13y + 0.2f * rb[122];
        const float hrz = n13z + 0.2f * rb[125];

        // masked exp(-d2) accumulate; `special` only for pair (left6, right6)
        auto acc = [&](float p0x, float p0y, float p0z,
                       float p1x, float p1y, float p1z,
                       float q0x, float q0y, float q0z,
                       float q1x, float q1y, float q1z, bool special) {
            const float d2 = cap_dist2(p0x,p0y,p0z, p1x,p1y,p1z,
                                       q0x,q0y,q0z, q1x,q1y,q1z);
            const bool m = special ? (d2 > 0.09f)
                                   : ((d2 < 0.01f) && (d2 > 0.0f));
            sum += m ? __expf(-d2) : 0.0f;
        };

        // left segs j: (n0,n1)..(n5,n6),(n6,handL); right segs i: (n7,n8)..(n13,handR)
        #define LROW(QX0,QY0,QZ0,QX1,QY1,QZ1,SP)                                  \
            acc(n0x,n0y,n0z, n1x,n1y,n1z, QX0,QY0,QZ0, QX1,QY1,QZ1, false);       \
            acc(n1x,n1y,n1z, n2x,n2y,n2z, QX0,QY0,QZ0, QX1,QY1,QZ1, false);       \
            acc(n2x,n2y,n2z, n3x,n3y,n3z, QX0,QY0,QZ0, QX1,QY1,QZ1, false);       \
            acc(n3x,n3y,n3z, n4x,n4y,n4z, QX0,QY0,QZ0, QX1,QY1,QZ1, false);       \
            acc(n4x,n4y,n4z, n5x,n5y,n5z, QX0,QY0,QZ0, QX1,QY1,QZ1, false);       \
            acc(n5x,n5y,n5z, n6x,n6y,n6z, QX0,QY0,QZ0, QX1,QY1,QZ1, false);       \
            acc(n6x,n6y,n6z, hlx,hly,hlz, QX0,QY0,QZ0, QX1,QY1,QZ1, SP);

        LROW(n7x, n7y, n7z,  n8x, n8y, n8z,  false)   // i=0
        LROW(n8x, n8y, n8z,  n9x, n9y, n9z,  false)   // i=1
        LROW(n9x, n9y, n9z,  n10x,n10y,n10z, false)   // i=2
        LROW(n10x,n10y,n10z, n11x,n11y,n11z, false)   // i=3
        LROW(n11x,n11y,n11z, n12x,n12y,n12z, false)   // i=4
        LROW(n12x,n12y,n12z, n13x,n13y,n13z, false)   // i=5
        LROW(n13x,n13y,n13z, hrx, hry, hrz,  true)    // i=6 (special at j=6)
        #undef LROW
    }

    // ---- reduction: wave shuffle -> LDS -> one atomic per block ----
    #pragma unroll
    for (int off = 32; off > 0; off >>= 1)
        sum += __shfl_down(sum, off, 64);
    const int wave = tid >> 6;
    if ((tid & 63) == 0) wsum[wave] = sum;
    __syncthreads();
    if (tid == 0) {
        float s = (wsum[0] + wsum[1]) + (wsum[2] + wsum[3]);
        atomicAdd(out, s * (1.0f / 262144.0f));  // exact pow2 scale = /B
    }
}

extern "C" void kernel_launch(void* const* d_in, const int* in_sizes, int n_in,
                              void* d_out, int out_size, void* d_ws, size_t ws_size,
                              hipStream_t stream) {
    const float* pos = (const float*)d_in[0];   // (B,14,3) f32
    const float* rot = (const float*)d_in[1];   // (B,14,9) f32
    float* out = (float*)d_out;

    const int B = in_sizes[0] / 42;             // 262144
    hipMemsetAsync(out, 0, sizeof(float), stream);

    const int grid = (B + 255) / 256;
    collision_loss_kernel<<<grid, 256, 0, stream>>>(pos, rot, out, B);
}

// Round 4
// 218.363 us; speedup vs baseline: 1.5352x; 1.0088x over previous
//
#include <hip/hip_runtime.h>

// CollisionLoss: B x (7 left) x (7 right) segment-segment squared distances,
// masked exp(-d2) sum / B.
// R4: R3's branchless Ericson cascade (exact, absmax 0.0) + coalesced LDS
// staging of the pos slab. R3's per-thread float2 loads had lane-stride 168B
// -> 64 cache lines per VMEM instruction (~16x TA/TD transaction
// amplification, ~1350 txns/wave); at 16 waves/CU that serialization is the
// ~65us vs ~10us-floor gap. Now: 128-thread block stages its contiguous
// 21504B pos slab into LDS with lane-consecutive float2 loads (4 txns/instr),
// threads read their 42 floats back from LDS (4-way bank alias on b64 =
// 1.58x, negligible). Rot gather is irreducible (24B needed per 504B row),
// issued before staging so its latency overlaps the LDS round-trip.
// LDS 21.5KB -> 7 blocks/CU = 14 waves/CU.

__device__ __forceinline__ float rcpf(float x) { return __builtin_amdgcn_rcpf(x); }
__device__ __forceinline__ float clamp01(float x) {
    return __builtin_amdgcn_fmed3f(x, 0.0f, 1.0f);
}

__device__ __forceinline__ float cap_dist2(
    float px0, float py0, float pz0, float px1, float py1, float pz1,
    float qx0, float qy0, float qz0, float qx1, float qy1, float qz1)
{
    const float dpx = px1 - px0, dpy = py1 - py0, dpz = pz1 - pz0;
    const float dqx = qx1 - qx0, dqy = qy1 - qy0, dqz = qz1 - qz0;
    const float rx  = px0 - qx0, ry  = py0 - qy0, rz  = pz0 - qz0;

    const float a = dpx*dpx + dpy*dpy + dpz*dpz;   // >0 w.p. 1 (gaussian)
    const float c = dqx*dqx + dqy*dqy + dqz*dqz;   // >0 w.p. 1
    const float b = dpx*dqx + dpy*dqy + dpz*dqz;
    const float d = dpx*rx + dpy*ry + dpz*rz;
    const float e = dqx*rx + dqy*ry + dqz*rz;
    const float det = a*c - b*b;

    const float rcp_a = rcpf(a);
    const float rcp_c = rcpf(c);

    // s0 = det>0 ? clamp01((be-cd)/det) : 0  (cndmask kills the inf/NaN path)
    const float f  = b*e - c*d;
    const float s0 = (det > 0.0f) ? clamp01(f * rcpf(det)) : 0.0f;

    const float tn = b*s0 + e;                 // t numerator (denominator c)
    const float t  = clamp01(tn * rcp_c);

    // recompute s only where t was clamped (two cndmasks); ties measure-zero
    const float sA = clamp01(-d * rcp_a);          // t clamped to 0
    const float sB = clamp01((b - d) * rcp_a);     // t clamped to 1
    const float s  = (tn < 0.0f) ? sA : ((tn > c) ? sB : s0);

    const float wx = rx + s*dpx - t*dqx;
    const float wy = ry + s*dpy - t*dqy;
    const float wz = rz + s*dpz - t*dqz;
    return wx*wx + wy*wy + wz*wz;
}

#define BT 128   // threads per block == batches per block (B % 128 == 0)

__global__ __launch_bounds__(BT) void collision_loss_kernel(
    const float* __restrict__ pos,
    const float* __restrict__ rot,
    float* __restrict__ out)
{
    __shared__ float2 sbuf[BT * 21];   // block's pos slab, 21504 B, linear mirror
    __shared__ float wsum[2];

    const int tid       = threadIdx.x;
    const int blockBase = blockIdx.x * BT;
    const int b         = blockBase + tid;

    // ---- rot gather first: 6 scattered dwords, latency overlaps staging ----
    const float* rb = rot + (size_t)b * 126;
    const float r6x = rb[ 56], r6y = rb[ 59], r6z = rb[ 62];  // node 6 col2
    const float rdx = rb[119], rdy = rb[122], rdz = rb[125];  // node13 col2

    // ---- coalesced stage: slab float2 index k*BT+tid, lanes consecutive ----
    const float2* g2 = reinterpret_cast<const float2*>(pos + (size_t)blockBase * 42);
    #pragma unroll
    for (int k = 0; k < 21; ++k) {
        const int idx = k * BT + tid;          // 0..2687, exact (21*128)
        sbuf[idx] = g2[idx];                   // ds_write_b64, conflict-free
    }
    __syncthreads();

    // ---- readback own 42 floats: thread's float2s are slab[tid*21 .. +21) ----
    const float2* m2 = sbuf + tid * 21;
    const float2 u0  = m2[0],  u1  = m2[1],  u2  = m2[2],  u3  = m2[3];
    const float2 u4  = m2[4],  u5  = m2[5],  u6  = m2[6],  u7  = m2[7];
    const float2 u8  = m2[8],  u9  = m2[9],  u10 = m2[10], u11 = m2[11];
    const float2 u12 = m2[12], u13 = m2[13], u14 = m2[14], u15 = m2[15];
    const float2 u16 = m2[16], u17 = m2[17], u18 = m2[18], u19 = m2[19];
    const float2 u20 = m2[20];

    // node n -> float indices 3n..3n+2; float f lives in u(f/2).(x|y)
    const float n0x=u0.x,  n0y=u0.y,  n0z=u1.x;
    const float n1x=u1.y,  n1y=u2.x,  n1z=u2.y;
    const float n2x=u3.x,  n2y=u3.y,  n2z=u4.x;
    const float n3x=u4.y,  n3y=u5.x,  n3z=u5.y;
    const float n4x=u6.x,  n4y=u6.y,  n4z=u7.x;
    const float n5x=u7.y,  n5y=u8.x,  n5z=u8.y;
    const float n6x=u9.x,  n6y=u9.y,  n6z=u10.x;
    const float n7x=u10.y, n7y=u11.x, n7z=u11.y;
    const float n8x=u12.x, n8y=u12.y, n8z=u13.x;
    const float n9x=u13.y, n9y=u14.x, n9z=u14.y;
    const float n10x=u15.x, n10y=u15.y, n10z=u16.x;
    const float n11x=u16.y, n11y=u17.x, n11z=u17.y;
    const float n12x=u18.x, n12y=u18.y, n12z=u19.x;
    const float n13x=u19.y, n13y=u20.x, n13z=u20.y;

    const float hlx = n6x  + 0.2f * r6x;   // handL = node6  + 0.2*col2
    const float hly = n6y  + 0.2f * r6y;
    const float hlz = n6z  + 0.2f * r6z;
    const float hrx = n13x + 0.2f * rdx;   // handR = node13 + 0.2*col2
    const float hry = n13y + 0.2f * rdy;
    const float hrz = n13z + 0.2f * rdz;

    float sum = 0.0f;

    // masked exp(-d2) accumulate; `special` only for pair (left6, right6)
    auto acc = [&](float p0x, float p0y, float p0z,
                   float p1x, float p1y, float p1z,
                   float q0x, float q0y, float q0z,
                   float q1x, float q1y, float q1z, bool special) {
        const float d2 = cap_dist2(p0x,p0y,p0z, p1x,p1y,p1z,
                                   q0x,q0y,q0z, q1x,q1y,q1z);
        const bool m = special ? (d2 > 0.09f)
                               : ((d2 < 0.01f) && (d2 > 0.0f));
        sum += m ? __expf(-d2) : 0.0f;
    };

    // left segs j: (n0,n1)..(n5,n6),(n6,handL); right segs i: (n7,n8)..(n13,handR)
    #define LROW(QX0,QY0,QZ0,QX1,QY1,QZ1,SP)                                  \
        acc(n0x,n0y,n0z, n1x,n1y,n1z, QX0,QY0,QZ0, QX1,QY1,QZ1, false);       \
        acc(n1x,n1y,n1z, n2x,n2y,n2z, QX0,QY0,QZ0, QX1,QY1,QZ1, false);       \
        acc(n2x,n2y,n2z, n3x,n3y,n3z, QX0,QY0,QZ0, QX1,QY1,QZ1, false);       \
        acc(n3x,n3y,n3z, n4x,n4y,n4z, QX0,QY0,QZ0, QX1,QY1,QZ1, false);       \
        acc(n4x,n4y,n4z, n5x,n5y,n5z, QX0,QY0,QZ0, QX1,QY1,QZ1, false);       \
        acc(n5x,n5y,n5z, n6x,n6y,n6z, QX0,QY0,QZ0, QX1,QY1,QZ1, false);       \
        acc(n6x,n6y,n6z, hlx,hly,hlz, QX0,QY0,QZ0, QX1,QY1,QZ1, SP);

    LROW(n7x, n7y, n7z,  n8x, n8y, n8z,  false)   // i=0
    LROW(n8x, n8y, n8z,  n9x, n9y, n9z,  false)   // i=1
    LROW(n9x, n9y, n9z,  n10x,n10y,n10z, false)   // i=2
    LROW(n10x,n10y,n10z, n11x,n11y,n11z, false)   // i=3
    LROW(n11x,n11y,n11z, n12x,n12y,n12z, false)   // i=4
    LROW(n12x,n12y,n12z, n13x,n13y,n13z, false)   // i=5
    LROW(n13x,n13y,n13z, hrx, hry, hrz,  true)    // i=6 (special at j=6)
    #undef LROW

    // ---- reduction: wave shuffle -> LDS -> one atomic per block ----
    #pragma unroll
    for (int off = 32; off > 0; off >>= 1)
        sum += __shfl_down(sum, off, 64);
    const int wave = tid >> 6;                 // 0..1
    if ((tid & 63) == 0) wsum[wave] = sum;
    __syncthreads();
    if (tid == 0) {
        atomicAdd(out, (wsum[0] + wsum[1]) * (1.0f / 262144.0f));  // /B exact
    }
}

extern "C" void kernel_launch(void* const* d_in, const int* in_sizes, int n_in,
                              void* d_out, int out_size, void* d_ws, size_t ws_size,
                              hipStream_t stream) {
    const float* pos = (const float*)d_in[0];   // (B,14,3) f32
    const float* rot = (const float*)d_in[1];   // (B,14,9) f32
    float* out = (float*)d_out;

    const int B = in_sizes[0] / 42;             // 262144 (multiple of 128)
    hipMemsetAsync(out, 0, sizeof(float), stream);

    collision_loss_kernel<<<B / BT, BT, 0, stream>>>(pos, rot, out);
}